// Round 11
// baseline (738.390 us; speedup 1.0000x reference)
//
#include <hip/hip_runtime.h>
#include <stdint.h>

#define N_NODES 100000
#define N_EDGES 1600000
#define FDIM 128
#define NH 8
#define NCLS 3
#define NB 782      // buckets of 128 nodes: bucket = dst >> 7
#define BCAP 4096   // fixed slice capacity per bucket (mean 2048, sd ~45)

static constexpr float SCALE = 0.25f; // D^-0.5, D=16

typedef _Float16 f16x8 __attribute__((ext_vector_type(8)));
typedef float    f32x4 __attribute__((ext_vector_type(4)));

// ---------------- binned append + node histogram (single pass over edges) ----------------
// binb record: { src_bits, dst_bits, ea0, ea1 } at binb[bkt*BCAP + rank]
__global__ __launch_bounds__(256) void k_bin(const int* __restrict__ ei,
                                             const float* __restrict__ ea,
                                             int* __restrict__ bcur,
                                             int* __restrict__ cnt,
                                             float4* __restrict__ binb) {
    __shared__ int lcnt[NB];
    __shared__ int lbase[NB];
    for (int i = threadIdx.x; i < NB; i += 256) lcnt[i] = 0;
    __syncthreads();
    int e0 = blockIdx.x * 1024;
    int rnk[4], bkt[4], src[4], dst[4];
    float2 eav[4];
#pragma unroll
    for (int j = 0; j < 4; ++j) {
        int e = e0 + j * 256 + threadIdx.x;
        if (e < N_EDGES) {
            src[j] = ei[e];
            dst[j] = ei[N_EDGES + e];
            eav[j] = *(const float2*)(ea + (long)e * 2);
            bkt[j] = dst[j] >> 7;
            rnk[j] = atomicAdd(&lcnt[bkt[j]], 1);
            atomicAdd(&cnt[dst[j]], 1);
        } else bkt[j] = -1;
    }
    __syncthreads();
    for (int i = threadIdx.x; i < NB; i += 256)
        if (lcnt[i]) lbase[i] = atomicAdd(&bcur[i], lcnt[i]);
    __syncthreads();
#pragma unroll
    for (int j = 0; j < 4; ++j) {
        if (bkt[j] >= 0) {
            int pos = bkt[j] * BCAP + lbase[bkt[j]] + rnk[j];
            binb[pos] = make_float4(__int_as_float(src[j]), __int_as_float(dst[j]),
                                    eav[j].x, eav[j].y);
        }
    }
}

// ---------------- prep: block 0 = single-block scan cnt->row_start; blocks 1..64 = W transposes ----------------
__global__ __launch_bounds__(1024) void k_prep(const int* __restrict__ cnt,
                                               int* __restrict__ row_start,
                                               const float* __restrict__ Wqkv,
                                               const float* __restrict__ Wout,
                                               _Float16* __restrict__ Wqkv_t,  // [384][128]
                                               _Float16* __restrict__ Wout_t) { // [128][128]
    if (blockIdx.x == 0) {
        __shared__ int sd[1024];
        const int NPT = 98; // 1024*98 >= 100000
        int t = threadIdx.x;
        int base = t * NPT;
        int s = 0;
        for (int i = 0; i < NPT; ++i) {
            int idx = base + i;
            if (idx < N_NODES) s += cnt[idx];
        }
        sd[t] = s;
        __syncthreads();
        for (int off = 1; off < 1024; off <<= 1) {
            int v = (t >= off) ? sd[t - off] : 0;
            __syncthreads();
            sd[t] += v;
            __syncthreads();
        }
        int run = sd[t] - s; // exclusive prefix
        for (int i = 0; i < NPT; ++i) {
            int idx = base + i;
            if (idx < N_NODES) { row_start[idx] = run; run += cnt[idx]; }
        }
        if (t == 0) row_start[N_NODES] = N_EDGES;
    } else {
        int i = (blockIdx.x - 1) * 1024 + threadIdx.x; // 0..65535
        if (i < 128 * 384) {
            int k = i / 384, n = i % 384;
            Wqkv_t[(long)n * 128 + k] = (_Float16)Wqkv[i];
        } else {
            int j = i - 128 * 384;
            int k = j / 128, n = j % 128;
            Wout_t[(long)n * 128 + k] = (_Float16)Wout[j];
        }
    }
}

// ---------------- fine scatter within bucket (one block per bucket) ----------------
// se4 = { src_bits, ea0, ea1, pad }; writes confined to ~32KB L2-resident window
__global__ __launch_bounds__(256) void k_fine(const float4* __restrict__ binb,
                                              const int* __restrict__ bcnt,
                                              const int* __restrict__ row_start,
                                              float4* __restrict__ se4) {
    __shared__ int cur[128];
    int b = blockIdx.x;
    int n0 = b << 7;
    int t = threadIdx.x;
    if (t < 128) {
        int n = n0 + t;
        cur[t] = (n < N_NODES) ? row_start[n] : 0;
    }
    __syncthreads();
    int p0 = b * BCAP, p1 = b * BCAP + bcnt[b];
    for (int p = p0 + t; p < p1; p += 256) {
        float4 r = binb[p];
        int d = __float_as_int(r.y);
        int pos = atomicAdd(&cur[d - n0], 1);
        se4[pos] = make_float4(r.x, r.z, r.w, 0.f);
    }
}

// ---------------- MFMA qkv GEMM: x[N x 128] (fp32, converted inline) @ Wt -> q (f32), kv (f16) ----------------
// col-split: wave w owns col-frags w*6..w*6+5 (96 cols), all 64 rows of the block.
__global__ __launch_bounds__(256) void k_mm_qkv(const float* __restrict__ x,
                                                const _Float16* __restrict__ Wt, // [384][128]
                                                float* __restrict__ q_tab,
                                                _Float16* __restrict__ kv_h) {
    int wave = threadIdx.x >> 6, l = threadIdx.x & 63;
    int row0 = blockIdx.x * 64;
    int lr = l & 15, lg = l >> 4;

    f32x4 acc[4][6];
#pragma unroll
    for (int rf = 0; rf < 4; ++rf)
#pragma unroll
        for (int c = 0; c < 6; ++c) acc[rf][c] = (f32x4){0.f, 0.f, 0.f, 0.f};

#pragma unroll
    for (int kk = 0; kk < 4; ++kk) {
        f16x8 a[4];
#pragma unroll
        for (int rf = 0; rf < 4; ++rf) {
            int row = row0 + rf * 16 + lr;
            if (row < N_NODES) {
                const float* xb = x + (long)row * 128 + lg * 8 + kk * 32;
                float4 v0 = *(const float4*)(xb);
                float4 v1 = *(const float4*)(xb + 4);
                a[rf] = (f16x8){ (_Float16)v0.x, (_Float16)v0.y, (_Float16)v0.z, (_Float16)v0.w,
                                 (_Float16)v1.x, (_Float16)v1.y, (_Float16)v1.z, (_Float16)v1.w };
            } else a[rf] = (f16x8){};
        }
        f16x8 b[6];
#pragma unroll
        for (int c = 0; c < 6; ++c) {
            int wc = wave * 6 + c;
            b[c] = *(const f16x8*)(Wt + (long)(wc * 16 + lr) * 128 + lg * 8 + kk * 32);
        }
#pragma unroll
        for (int rf = 0; rf < 4; ++rf)
#pragma unroll
            for (int c = 0; c < 6; ++c)
                acc[rf][c] = __builtin_amdgcn_mfma_f32_16x16x32_f16(a[rf], b[c], acc[rf][c], 0, 0, 0);
    }

#pragma unroll
    for (int rf = 0; rf < 4; ++rf) {
#pragma unroll
        for (int c = 0; c < 6; ++c) {
            int col = (wave * 6 + c) * 16 + lr;
#pragma unroll
            for (int j = 0; j < 4; ++j) {
                int row = row0 + rf * 16 + lg * 4 + j;
                if (row < N_NODES) {
                    float v = acc[rf][c][j];
                    if (col < 128)       q_tab[(long)row * 128 + col] = v;
                    else if (col < 256)  kv_h[(long)row * 256 + (col - 128)] = (_Float16)v;
                    else                 kv_h[(long)row * 256 + 128 + (col - 256)] = (_Float16)v;
                }
            }
        }
    }
}

// ---------------- per-node edge attention (fp16 kv, fp16 agg out) ----------------
__global__ __launch_bounds__(256) void k_attn(const float* __restrict__ q_tab,
                                              const _Float16* __restrict__ kv_tab,
                                              const float4* __restrict__ se4,
                                              const int* __restrict__ row_start,
                                              const float* __restrict__ Wedge,
                                              _Float16* __restrict__ agg_h) {
    int wave = threadIdx.x >> 6;
    int lane = threadIdx.x & 63;
    int node = blockIdx.x * 4 + wave;
    if (node >= N_NODES) return;

    int g  = lane >> 4;      // edge group 0..3
    int gl = lane & 15;      // dims gl*8 .. gl*8+7
    int h  = gl >> 1;        // head of these 8 dims

    int p0 = row_start[node], p1 = row_start[node + 1];
    if (p0 == p1) { // degree-0: zeros
        if (g == 0) *(f16x8*)(agg_h + (long)node * 128 + gl * 8) = (f16x8){};
        return;
    }

    float we0 = Wedge[h];
    float we1 = Wedge[8 + h];
    const float* qb = q_tab + (long)node * 128 + gl * 8;
    float4 qa  = *(const float4*)(qb);
    float4 qbv = *(const float4*)(qb + 4);

    float a0=0.f,a1=0.f,a2=0.f,a3=0.f,a4=0.f,a5=0.f,a6=0.f,a7=0.f;
    float den = 0.f;

    int last = p1 - 1;
    float4 rec = se4[min(p0 + g, last)];
    for (int p = p0; p < p1; p += 4) {
        float4 cur = rec;
        int pn = p + 4;
        if (pn < p1) rec = se4[min(pn + g, last)];

        bool valid = (p + g) < p1;
        int src = __float_as_int(cur.x);
        const _Float16* kvb = kv_tab + (long)src * 256 + gl * 8;
        f16x8 kh = *(const f16x8*)(kvb);
        f16x8 vh = *(const f16x8*)(kvb + 128);

        float part = qa.x  * (float)kh[0] + qa.y  * (float)kh[1]
                   + qa.z  * (float)kh[2] + qa.w  * (float)kh[3]
                   + qbv.x * (float)kh[4] + qbv.y * (float)kh[5]
                   + qbv.z * (float)kh[6] + qbv.w * (float)kh[7];
        part += __shfl_xor(part, 1); // complete 16-dim head dot within lane pair

        float s = part * SCALE + cur.y * we0 + cur.z * we1;
        float w = valid ? __expf(s) : 0.f;
        den += w;
        a0 += w * (float)vh[0]; a1 += w * (float)vh[1];
        a2 += w * (float)vh[2]; a3 += w * (float)vh[3];
        a4 += w * (float)vh[4]; a5 += w * (float)vh[5];
        a6 += w * (float)vh[6]; a7 += w * (float)vh[7];
    }

#pragma unroll
    for (int off = 16; off <= 32; off <<= 1) {
        a0 += __shfl_xor(a0, off); a1 += __shfl_xor(a1, off);
        a2 += __shfl_xor(a2, off); a3 += __shfl_xor(a3, off);
        a4 += __shfl_xor(a4, off); a5 += __shfl_xor(a5, off);
        a6 += __shfl_xor(a6, off); a7 += __shfl_xor(a7, off);
        den += __shfl_xor(den, off);
    }

    if (g == 0) {
        float inv = 1.0f / (den + 1e-16f);
        f16x8 o = { (_Float16)(a0 * inv), (_Float16)(a1 * inv),
                    (_Float16)(a2 * inv), (_Float16)(a3 * inv),
                    (_Float16)(a4 * inv), (_Float16)(a5 * inv),
                    (_Float16)(a6 * inv), (_Float16)(a7 * inv) };
        *(f16x8*)(agg_h + (long)node * 128 + gl * 8) = o;
    }
}

// ---------------- fused out-proj + residual + LN + MLP ----------------
// phase A: MFMA out-proj (wave w owns col-frags w*2,w*2+1; all 64 rows), h -> LDS
// phase B: per-row LN then MLP (wave w owns rows w*16..w*16+15)
__global__ __launch_bounds__(256) void k_mm_fuse(const _Float16* __restrict__ agg_h,
                                                 const _Float16* __restrict__ Wot, // [128][128]
                                                 const float* __restrict__ bout,
                                                 const float* __restrict__ x,
                                                 const float* __restrict__ ln_w,
                                                 const float* __restrict__ ln_b,
                                                 const float* __restrict__ Wc1,
                                                 const float* __restrict__ bc1,
                                                 const float* __restrict__ Wc2,
                                                 const float* __restrict__ bc2,
                                                 float* __restrict__ out) {
    __shared__ float hb[64][132]; // +4 pad
    int wave = threadIdx.x >> 6, l = threadIdx.x & 63;
    int row0 = blockIdx.x * 64;
    int lr = l & 15, lg = l >> 4;

    // ---- phase A: out-projection ----
    f32x4 acc[4][2];
#pragma unroll
    for (int rf = 0; rf < 4; ++rf)
#pragma unroll
        for (int c = 0; c < 2; ++c) acc[rf][c] = (f32x4){0.f, 0.f, 0.f, 0.f};

#pragma unroll
    for (int kk = 0; kk < 4; ++kk) {
        f16x8 a[4];
#pragma unroll
        for (int rf = 0; rf < 4; ++rf) {
            int row = row0 + rf * 16 + lr;
            a[rf] = (row < N_NODES) ? *(const f16x8*)(agg_h + (long)row * 128 + lg * 8 + kk * 32)
                                    : (f16x8){};
        }
        f16x8 b[2];
#pragma unroll
        for (int c = 0; c < 2; ++c) {
            int wc = wave * 2 + c;
            b[c] = *(const f16x8*)(Wot + (long)(wc * 16 + lr) * 128 + lg * 8 + kk * 32);
        }
#pragma unroll
        for (int rf = 0; rf < 4; ++rf)
#pragma unroll
            for (int c = 0; c < 2; ++c)
                acc[rf][c] = __builtin_amdgcn_mfma_f32_16x16x32_f16(a[rf], b[c], acc[rf][c], 0, 0, 0);
    }

#pragma unroll
    for (int rf = 0; rf < 4; ++rf) {
#pragma unroll
        for (int c = 0; c < 2; ++c) {
            int col = (wave * 2 + c) * 16 + lr;
            float bv = bout[col];
#pragma unroll
            for (int j = 0; j < 4; ++j) {
                int lrow = rf * 16 + lg * 4 + j;
                int row = row0 + lrow;
                hb[lrow][col] = (row < N_NODES)
                    ? acc[rf][c][j] + bv + x[(long)row * 128 + col] : 0.f;
            }
        }
    }
    __syncthreads();

    // ---- phase B: LN + MLP, wave owns rows wave*16 .. wave*16+15 ----
    float2 lw = *(const float2*)(ln_w + l * 2);
    float2 lb = *(const float2*)(ln_b + l * 2);
    float b1 = bc1[l];

#pragma unroll
    for (int grp = 0; grp < 4; ++grp) {
        int lrow0 = wave * 16 + grp * 4;
        // LN for 4 rows
#pragma unroll
        for (int nb = 0; nb < 4; ++nb) {
            int lrow = lrow0 + nb;
            float hx = hb[lrow][l * 2];
            float hy = hb[lrow][l * 2 + 1];
            float s = hx + hy;
#pragma unroll
            for (int off = 32; off > 0; off >>= 1) s += __shfl_xor(s, off);
            float mu = s * (1.0f / 128.0f);
            float dx = hx - mu, dy = hy - mu;
            float s2 = dx * dx + dy * dy;
#pragma unroll
            for (int off = 32; off > 0; off >>= 1) s2 += __shfl_xor(s2, off);
            float rstd = rsqrtf(s2 * (1.0f / 128.0f) + 1e-5f);
            hb[lrow][l * 2]     = dx * rstd * lw.x + lb.x;
            hb[lrow][l * 2 + 1] = dy * rstd * lw.y + lb.y;
        }
        // MLP for the 4 rows (lane = hidden unit)
        float macc[4] = { b1, b1, b1, b1 };
#pragma unroll 4
        for (int c = 0; c < 128; ++c) {
            float w = Wc1[c * 64 + l];
            macc[0] += hb[lrow0 + 0][c] * w;
            macc[1] += hb[lrow0 + 1][c] * w;
            macc[2] += hb[lrow0 + 2][c] * w;
            macc[3] += hb[lrow0 + 3][c] * w;
        }
#pragma unroll
        for (int nb = 0; nb < 4; ++nb) {
            int row = row0 + lrow0 + nb;
            float a = fmaxf(macc[nb], 0.f);
#pragma unroll
            for (int c2 = 0; c2 < NCLS; ++c2) {
                float pv = a * Wc2[l * 3 + c2];
#pragma unroll
                for (int off = 32; off > 0; off >>= 1) pv += __shfl_xor(pv, off);
                if (l == 0 && row < N_NODES) out[(long)row * 3 + c2] = pv + bc2[c2];
            }
        }
    }
}

extern "C" void kernel_launch(void* const* d_in, const int* in_sizes, int n_in,
                              void* d_out, int out_size, void* d_ws, size_t ws_size,
                              hipStream_t stream) {
    const float* x         = (const float*)d_in[0];
    const int*   edge_index= (const int*)d_in[1];   // harness stages integers as int32
    const float* edge_attr = (const float*)d_in[2];
    const float* Wqkv      = (const float*)d_in[3];
    const float* Wedge     = (const float*)d_in[4];
    const float* Wout      = (const float*)d_in[5];
    const float* bout      = (const float*)d_in[6];
    const float* ln_w      = (const float*)d_in[7];
    const float* ln_b      = (const float*)d_in[8];
    const float* Wc1       = (const float*)d_in[9];
    const float* bc1       = (const float*)d_in[10];
    const float* Wc2       = (const float*)d_in[11];
    const float* bc2       = (const float*)d_in[12];
    float* out = (float*)d_out;

    // workspace layout (~206 MB)
    char* ws = (char*)d_ws;
    size_t o = 0;
    auto alloc = [&](size_t bytes) -> char* {
        char* p = ws + o;
        o = (o + bytes + 255) & ~(size_t)255;
        return p;
    };
    int*       cnt       = (int*)alloc((size_t)N_NODES * 4);
    int*       bcur      = (int*)alloc((size_t)NB * 4);     // adjacent to cnt: one memset covers both
    int*       row_start = (int*)alloc((size_t)(N_NODES + 1) * 4);
    float4*    binb      = (float4*)alloc((size_t)NB * BCAP * 16);
    float4*    se4       = (float4*)alloc((size_t)N_EDGES * 16);
    _Float16*  Wqkv_t    = (_Float16*)alloc((size_t)384 * 128 * 2);
    _Float16*  Wout_t    = (_Float16*)alloc((size_t)128 * 128 * 2);
    float*     q_tab     = (float*)alloc((size_t)N_NODES * 128 * 4);
    _Float16*  kv_h      = (_Float16*)alloc((size_t)N_NODES * 256 * 2);
    _Float16*  agg_h     = (_Float16*)alloc((size_t)N_NODES * 128 * 2);
    (void)ws_size; (void)in_sizes; (void)n_in; (void)out_size;

    size_t zspan = (size_t)((char*)bcur - (char*)cnt) + (size_t)NB * 4;
    hipMemsetAsync(cnt, 0, zspan, stream);

    k_bin<<<1563, 256, 0, stream>>>(edge_index, edge_attr, bcur, cnt, binb);
    k_prep<<<65, 1024, 0, stream>>>(cnt, row_start, Wqkv, Wout, Wqkv_t, Wout_t);
    k_fine<<<NB, 256, 0, stream>>>(binb, bcur, row_start, se4);

    k_mm_qkv<<<1563, 256, 0, stream>>>(x, Wqkv_t, q_tab, kv_h);
    k_attn<<<25000, 256, 0, stream>>>(q_tab, kv_h, se4, row_start, Wedge, agg_h);
    k_mm_fuse<<<1563, 256, 0, stream>>>(agg_h, Wout_t, bout, x, ln_w, ln_b,
                                        Wc1, bc1, Wc2, bc2, out);
}